// Round 1
// 600.003 us; speedup vs baseline: 1.0264x; 1.0264x over previous
//
#include <hip/hip_runtime.h>

#define BB 16
#define CC 384
#define CH 64
#define CF 193
#define HW 16384   // 128*128

// ---------------- Kernel 1: global average pool ----------------
// x: [B, C, H, W] fp32, each plane of 16384 floats contiguous (64 KB).
// One block per plane, 256 threads, float4 loads (16 iters).
// BW-bound floor: 402.6 MB / ~6.5 TB/s ~= 62 us. Already at roofline.
__global__ __launch_bounds__(256) void pool_kernel(const float4* __restrict__ x,
                                                   float* __restrict__ y0) {
    const int plane = blockIdx.x;                 // b*C + c
    const float4* p = x + (size_t)plane * (HW / 4);
    const int t = threadIdx.x;

    float s = 0.f;
#pragma unroll
    for (int r = 0; r < HW / 4 / 256; ++r) {      // 16 iterations
        float4 v = p[t + 256 * r];
        s += v.x + v.y + v.z + v.w;
    }

    // wave64 reduce
#pragma unroll
    for (int off = 32; off > 0; off >>= 1) s += __shfl_down(s, off);

    __shared__ float red[4];
    const int wid = t >> 6, lane = t & 63;
    if (lane == 0) red[wid] = s;
    __syncthreads();
    if (t == 0) {
        float tot = red[0] + red[1] + red[2] + red[3];
        y0[plane] = tot * (1.0f / (float)HW);
    }
}

// ---------------- Kernel 2: the head (all the tiny math) ----------------
// One block per batch element, 384 threads (6 waves).
// v2: latency-bound phases restructured:
//   - phase 2 (h): 384-thread split (64 outputs x 6 partials) instead of 64 serial threads
//   - phase 4 (s1/s2/rfft dots): wave-split bins, lanes split c -> Ws1/Ws2 loads fully
//     coalesced (256B/instr) instead of 64-line scatters; butterfly reduce; transcendentals
//     done in a separate 193-thread-parallel pass.
__global__ __launch_bounds__(384) void head_kernel(
    const float* __restrict__ y0g,
    const float* __restrict__ W1,  const float* __restrict__ b1,
    const float* __restrict__ W2,  const float* __restrict__ b2,
    const float* __restrict__ Ws1, const float* __restrict__ bs1,
    const float* __restrict__ Ws2, const float* __restrict__ bs2,
    float* __restrict__ out)
{
    __shared__ float y0[CC], h[CH], y[CC];
    __shared__ float ct[CC], st[CC];
    __shared__ float rr[CF + 1], ri[CF + 1];
    __shared__ float reS[CF], imS[CF], a1S[CF], a2S[CF];
    __shared__ float hp[6][CH];

    const int b = blockIdx.x, t = threadIdx.x;
    const int wid = t >> 6, lane = t & 63;

    // stage y0 + twiddle tables (cos/sin of 2*pi*t/384)
    y0[t] = y0g[b * CC + t];
    {
        float ang = (float)t * (6.283185307179586f / (float)CC);
        float sv, cv;
        sincosf(ang, &sv, &cv);
        st[t] = sv; ct[t] = cv;
    }
    __syncthreads();

    // ---- phase 2: h = relu(y0 @ W1c^T + b1), W1c[j,c] = W1[(j*384+c)*9+4]
    // 384 threads: output j = t&63, c-range part = t>>6 (64 c's each)
    {
        const int j = t & 63, part = t >> 6;
        const float* w  = W1 + ((size_t)j * CC + part * 64) * 9 + 4;
        const float* yy = y0 + part * 64;
        float acc = 0.f;
#pragma unroll 8
        for (int c = 0; c < 64; ++c) acc += yy[c] * w[c * 9];
        hp[part][j] = acc;
    }
    __syncthreads();
    if (t < CH) {
        float acc = b1[t] + hp[0][t] + hp[1][t] + hp[2][t]
                          + hp[3][t] + hp[4][t] + hp[5][t];
        h[t] = fmaxf(acc, 0.f);
    }
    __syncthreads();

    // ---- phase 3: y = sigmoid(h @ W2c^T + b2), W2c[c,j] = W2[(c*64+j)*9+4]
    {
        float acc = b2[t];
        const float* w = W2 + (size_t)t * CH * 9 + 4;
#pragma unroll 8
        for (int j = 0; j < CH; ++j) acc += h[j] * w[j * 9];
        y[t] = 1.f / (1.f + expf(-acc));
    }
    __syncthreads();

    // ---- phase 4a: per-wave bins; lanes split c -> coalesced Ws1/Ws2 loads
    for (int k = wid; k < CF; k += 6) {
        const float* w1r = Ws1 + (size_t)k * CC;
        const float* w2r = Ws2 + (size_t)k * CC;
        int m   = (k * lane) % CC;        // (k*c) % 384 at c = lane
        int inc = (k << 6) % CC;          // step for c += 64
        float a1 = 0.f, a2 = 0.f, re = 0.f, im = 0.f;
#pragma unroll
        for (int i = 0; i < 6; ++i) {
            const int c = lane + (i << 6);
            float yc = y[c];
            a1 += yc * w1r[c];            // coalesced: 64 consecutive floats/wave
            a2 += yc * w2r[c];
            re += yc * ct[m];
            im -= yc * st[m];
            m += inc; if (m >= CC) m -= CC;
        }
        // wave64 butterfly reduce (4 values)
#pragma unroll
        for (int off = 32; off > 0; off >>= 1) {
            a1 += __shfl_down(a1, off);
            a2 += __shfl_down(a2, off);
            re += __shfl_down(re, off);
            im += __shfl_down(im, off);
        }
        if (lane == 0) { a1S[k] = a1; a2S[k] = a2; reS[k] = re; imS[k] = im; }
    }
    __syncthreads();

    // ---- phase 4b: transcendentals, 193-thread parallel
    if (t < CF) {
        float a1 = fmaxf(a1S[t] + bs1[t], 0.f);
        float a2 = fmaxf(a2S[t] + bs2[t], 0.f);
        float re = reS[t], im = imS[t];
        float amp = sqrtf(re * re + im * im) * a1;
        float pha = atan2f(im, re) * a2;
        float sp, cp;
        sincosf(pha, &sp, &cp);
        rr[t] = amp * cp;
        ri[t] = amp * sp;
    }
    __syncthreads();

    // ---- phase 5: irfft (real formula; Im of DC/Nyquist dropped) + final mul
    {
        float acc = 0.f;
        int m = 0;                                 // (k*t) % 384
        for (int k = 1; k < 192; ++k) {
            m += t; if (m >= CC) m -= CC;
            acc += rr[k] * ct[m] - ri[k] * st[m];
        }
        float nyq = (t & 1) ? -rr[192] : rr[192];
        float xr = (rr[0] + 2.f * acc + nyq) * (1.0f / (float)CC);
        out[b * CC + t] = xr * y[t];
    }
}

extern "C" void kernel_launch(void* const* d_in, const int* in_sizes, int n_in,
                              void* d_out, int out_size, void* d_ws, size_t ws_size,
                              hipStream_t stream) {
    const float4* x = (const float4*)d_in[0];
    const float* W1  = (const float*)d_in[1];
    const float* b1  = (const float*)d_in[2];
    const float* W2  = (const float*)d_in[3];
    const float* b2  = (const float*)d_in[4];
    const float* Ws1 = (const float*)d_in[5];
    const float* bs1 = (const float*)d_in[6];
    const float* Ws2 = (const float*)d_in[7];
    const float* bs2 = (const float*)d_in[8];
    float* out = (float*)d_out;

    float* y0 = (float*)d_ws;   // 6144 floats

    pool_kernel<<<BB * CC, 256, 0, stream>>>(x, y0);
    head_kernel<<<BB, 384, 0, stream>>>(y0, W1, b1, W2, b2, Ws1, bs1, Ws2, bs2, out);
}

// Round 2
// 563.920 us; speedup vs baseline: 1.0920x; 1.0640x over previous
//
#include <hip/hip_runtime.h>

#define BB 16
#define CC 384
#define CH 64
#define CF 193
#define HW 16384   // 128*128

#define POOL_BLOCKS (BB * CC)        // 6144
#define G1_BLOCKS 96                 // 24576 W1 center taps / 256
#define G2_BLOCKS 96                 // 24576 W2 center taps / 256

// workspace layout (floats):
//   [0, 6144)            y0[b*C + c]
//   [6144, 30720)        W1cT[c*64 + j]  = W1[j][c][1][1]   (c-major, lane=j coalesced)
//   [30720, 55296)       W2cT[j*384 + c] = W2[c][j][1][1]   (j-major, lane=c coalesced)
#define WS_Y0   0
#define WS_W1   6144
#define WS_W2   30720

// ---------------- Kernel 1: global average pool + weight gather ----------------
// Pool: one block per plane (64 KB), 256 threads, float4 loads. BW-roofline ~62 us.
// Gather: 192 extra blocks extract the 3x3 center taps into dense transposed
// matrices; scattered reads are latency-hidden across the pool's BW-bound dispatch.
__global__ __launch_bounds__(256) void pool_gather_kernel(
    const float4* __restrict__ x,
    const float* __restrict__ W1, const float* __restrict__ W2,
    float* __restrict__ ws)
{
    const int blk = blockIdx.x;
    const int t = threadIdx.x;

    if (blk < POOL_BLOCKS) {
        const float4* p = x + (size_t)blk * (HW / 4);
        float s = 0.f;
#pragma unroll
        for (int r = 0; r < HW / 4 / 256; ++r) {      // 16 iterations
            float4 v = p[t + 256 * r];
            s += v.x + v.y + v.z + v.w;
        }
#pragma unroll
        for (int off = 32; off > 0; off >>= 1) s += __shfl_down(s, off);

        __shared__ float red[4];
        const int wid = t >> 6, lane = t & 63;
        if (lane == 0) red[wid] = s;
        __syncthreads();
        if (t == 0) {
            float tot = red[0] + red[1] + red[2] + red[3];
            ws[WS_Y0 + blk] = tot * (1.0f / (float)HW);
        }
    } else if (blk < POOL_BLOCKS + G1_BLOCKS) {
        // W1cT[i] with i = c*64 + j  (coalesced write), read W1[j*3456 + c*9 + 4]
        const int i = (blk - POOL_BLOCKS) * 256 + t;
        const int j = i & 63, c = i >> 6;
        ws[WS_W1 + i] = W1[(size_t)j * (CC * 9) + c * 9 + 4];
    } else {
        // W2cT[i] with i = j*384 + c  (coalesced write), read W2[c*576 + j*9 + 4]
        const int i = (blk - POOL_BLOCKS - G1_BLOCKS) * 256 + t;
        const int j = i / CC, c = i - j * CC;
        ws[WS_W2 + i] = W2[(size_t)c * (CH * 9) + j * 9 + 4];
    }
}

// ---------------- Kernel 2: the head ----------------
// One block per batch element, 384 threads (6 waves).
// v3: phases 2/3 read pre-gathered dense transposed weights (coalesced);
//     phase 5 uses Chebyshev cos/sin recurrence (resync every 16 k) + packed
//     float2 rr/ri -> 1 broadcast ds_read_b64 per k instead of 4 b32 reads.
__global__ __launch_bounds__(384) void head_kernel(
    const float* __restrict__ ws,
    const float* __restrict__ b1,  const float* __restrict__ b2,
    const float* __restrict__ Ws1, const float* __restrict__ bs1,
    const float* __restrict__ Ws2, const float* __restrict__ bs2,
    float* __restrict__ out)
{
    __shared__ float y0[CC], h[CH], y[CC];
    __shared__ float ct[CC], st[CC];
    __shared__ float2 rrri[CF];
    __shared__ float reS[CF], imS[CF], a1S[CF], a2S[CF];
    __shared__ float hp[6][CH];

    const int b = blockIdx.x, t = threadIdx.x;
    const int wid = t >> 6, lane = t & 63;

    const float* __restrict__ w1cT = ws + WS_W1;
    const float* __restrict__ w2cT = ws + WS_W2;

    // stage y0 + twiddle tables (cos/sin of 2*pi*t/384)
    y0[t] = ws[WS_Y0 + b * CC + t];
    {
        float ang = (float)t * (6.283185307179586f / (float)CC);
        float sv, cv;
        sincosf(ang, &sv, &cv);
        st[t] = sv; ct[t] = cv;
    }
    __syncthreads();

    // ---- phase 2: h = relu(y0 @ W1c^T + b1); wave wid covers c in [wid*64, wid*64+64)
    // W1cT[c*64 + lane]: 64 consecutive floats per wave-load -> coalesced.
    {
        const float* w  = w1cT + wid * (64 * 64);
        const float* yy = y0 + wid * 64;
        float acc = 0.f;
#pragma unroll 8
        for (int c = 0; c < 64; ++c) acc = fmaf(yy[c], w[c * 64 + lane], acc);
        hp[wid][lane] = acc;
    }
    __syncthreads();
    if (t < CH) {
        float acc = b1[t] + hp[0][t] + hp[1][t] + hp[2][t]
                          + hp[3][t] + hp[4][t] + hp[5][t];
        h[t] = fmaxf(acc, 0.f);
    }
    __syncthreads();

    // ---- phase 3: y = sigmoid(h @ W2c^T + b2); W2cT[j*384 + t]: lanes consecutive t.
    {
        float acc = b2[t];
        const float* w = w2cT + t;
#pragma unroll 8
        for (int j = 0; j < CH; ++j) acc = fmaf(h[j], w[j * CC], acc);
        y[t] = 1.f / (1.f + expf(-acc));
    }
    __syncthreads();

    // ---- phase 4a: per-wave bins; lanes split c -> coalesced Ws1/Ws2 loads
    for (int k = wid; k < CF; k += 6) {
        const float* w1r = Ws1 + (size_t)k * CC;
        const float* w2r = Ws2 + (size_t)k * CC;
        int m   = (k * lane) % CC;        // (k*c) % 384 at c = lane
        int inc = (k << 6) % CC;          // step for c += 64
        float a1 = 0.f, a2 = 0.f, re = 0.f, im = 0.f;
#pragma unroll
        for (int i = 0; i < 6; ++i) {
            const int c = lane + (i << 6);
            float yc = y[c];
            a1 += yc * w1r[c];            // coalesced: 64 consecutive floats/wave
            a2 += yc * w2r[c];
            re += yc * ct[m];
            im -= yc * st[m];
            m += inc; if (m >= CC) m -= CC;
        }
#pragma unroll
        for (int off = 32; off > 0; off >>= 1) {
            a1 += __shfl_down(a1, off);
            a2 += __shfl_down(a2, off);
            re += __shfl_down(re, off);
            im += __shfl_down(im, off);
        }
        if (lane == 0) { a1S[k] = a1; a2S[k] = a2; reS[k] = re; imS[k] = im; }
    }
    __syncthreads();

    // ---- phase 4b: transcendentals, 193-thread parallel
    if (t < CF) {
        float a1 = fmaxf(a1S[t] + bs1[t], 0.f);
        float a2 = fmaxf(a2S[t] + bs2[t], 0.f);
        float re = reS[t], im = imS[t];
        float amp = sqrtf(re * re + im * im) * a1;
        float pha = atan2f(im, re) * a2;
        float sp, cp;
        sincosf(pha, &sp, &cp);
        rrri[t] = make_float2(amp * cp, amp * sp);
    }
    __syncthreads();

    // ---- phase 5: irfft via Chebyshev recurrence
    // c_{k+1} = 2*cos(th)*c_k - c_{k-1}, th = 2*pi*t/384; exact resync from the
    // twiddle table every 16 k. rr/ri packed -> one broadcast ds_read_b64 per k.
    {
        const float tc2 = 2.f * ct[t];
        float acc = 0.f;
        // groups g=0..10: k = 1+16g .. 16+16g  (covers 1..176)
        for (int g = 0; g < 11; ++g) {
            const int k0 = 1 + (g << 4);
            int mk = (k0 * t) % CC;
            int mk1 = mk + t; if (mk1 >= CC) mk1 -= CC;
            float c0 = ct[mk],  s0 = st[mk];
            float c1 = ct[mk1], s1 = st[mk1];
#pragma unroll
            for (int i = 0; i < 16; ++i) {
                float2 v = rrri[k0 + i];
                acc = fmaf(v.x, c0, acc);
                acc = fmaf(-v.y, s0, acc);
                float c2 = fmaf(tc2, c1, -c0);
                float s2 = fmaf(tc2, s1, -s0);
                c0 = c1; s0 = s1; c1 = c2; s1 = s2;
            }
        }
        // tail: k = 177..191
        {
            int mk = (177 * t) % CC;
            int mk1 = mk + t; if (mk1 >= CC) mk1 -= CC;
            float c0 = ct[mk],  s0 = st[mk];
            float c1 = ct[mk1], s1 = st[mk1];
#pragma unroll
            for (int i = 0; i < 15; ++i) {
                float2 v = rrri[177 + i];
                acc = fmaf(v.x, c0, acc);
                acc = fmaf(-v.y, s0, acc);
                float c2 = fmaf(tc2, c1, -c0);
                float s2 = fmaf(tc2, s1, -s0);
                c0 = c1; s0 = s1; c1 = c2; s1 = s2;
            }
        }
        float nyq = (t & 1) ? -rrri[192].x : rrri[192].x;
        float xr = (rrri[0].x + 2.f * acc + nyq) * (1.0f / (float)CC);
        out[b * CC + t] = xr * y[t];
    }
}

extern "C" void kernel_launch(void* const* d_in, const int* in_sizes, int n_in,
                              void* d_out, int out_size, void* d_ws, size_t ws_size,
                              hipStream_t stream) {
    const float4* x = (const float4*)d_in[0];
    const float* W1  = (const float*)d_in[1];
    const float* b1  = (const float*)d_in[2];
    const float* W2  = (const float*)d_in[3];
    const float* b2  = (const float*)d_in[4];
    const float* Ws1 = (const float*)d_in[5];
    const float* bs1 = (const float*)d_in[6];
    const float* Ws2 = (const float*)d_in[7];
    const float* bs2 = (const float*)d_in[8];
    float* out = (float*)d_out;

    float* ws = (float*)d_ws;

    pool_gather_kernel<<<POOL_BLOCKS + G1_BLOCKS + G2_BLOCKS, 256, 0, stream>>>(x, W1, W2, ws);
    head_kernel<<<BB, 384, 0, stream>>>(ws, b1, b2, Ws1, bs1, Ws2, bs2, out);
}